// Round 1
// baseline (202.670 us; speedup 1.0000x reference)
//
#include <hip/hip_runtime.h>
#include <stdint.h>

#define DEVI static __device__ __forceinline__

typedef unsigned short u16;
typedef short bf16x8 __attribute__((ext_vector_type(8)));
typedef u16 u16x8 __attribute__((ext_vector_type(8)));
typedef u16 u16x4 __attribute__((ext_vector_type(4)));
typedef float f32x4 __attribute__((ext_vector_type(4)));

// round-to-nearest-even float -> bf16 (no NaN handling needed for this data)
DEVI u16 f2bf(float f) {
    uint32_t u = __builtin_bit_cast(uint32_t, f);
    u += 0x7FFFu + ((u >> 16) & 1u);
    return (u16)(u >> 16);
}

struct GemmArgs {
    const void* A;        // fp32 or bf16(u16), row-major [M x K]
    long long aStrideBytes;   // per-batch stride in BYTES
    int lda;                  // elements
    const u16* Bm;        // [N x K] bf16 (i.e. B^T layout)
    long long bStrideElts;
    int ldb;
    int K;
    const float* bias;
    u16* outB;            // bf16 output (proj / pv)
    float* outF;          // fp32 output (logits e / final out)
    long long outFStride; // per-batch elements
    const float* qm; const float* md; const float* tauPtr; float scale;
    float* partials;      // [B*2048 * 16]
    u16* vt;              // V transposed dest [B][512][2048]
};

enum { EPI_PROJ = 0, EPI_PROJV = 1, EPI_LOGITS = 2, EPI_PV = 3, EPI_OUT = 4 };

// C[M,N] = A[M,K] @ B[N,K]^T, 128x128 tile, BK=32, 4 waves, 16x16x32 bf16 MFMA.
template <int EPI, bool AF32>
__global__ __launch_bounds__(256, 2) void gemm_bt(GemmArgs p) {
    __shared__ u16 As[128 * 32];
    __shared__ u16 Bs[128 * 32];
    __shared__ float redBuf[2][128];

    const int tid = threadIdx.x;
    const int lane = tid & 63;
    const int wave = tid >> 6;
    const int g = lane >> 4, lr = lane & 15;
    const int wr = wave >> 1, wc = wave & 1;
    const int z = blockIdx.z;
    const int rowBase = blockIdx.x * 128;
    const int colBase = blockIdx.y * 128;

    const char* Abase = (const char*)p.A + (size_t)z * p.aStrideBytes;
    const u16* Bbase = p.Bm + (size_t)z * p.bStrideElts;

    f32x4 acc[4][4] = {};

    const int nk = p.K >> 5;
    for (int kt = 0; kt < nk; ++kt) {
        const int kb = kt << 5;
        float4 areg[4];
        if (AF32) {
            // reg-stage A tile (128 rows x 32 fp32) with bf16 convert
            const float* Af = (const float*)Abase;
            const int arow = tid >> 1, kh = (tid & 1) << 4;
            const float* src = Af + (size_t)(rowBase + arow) * p.lda + kb + kh;
            #pragma unroll
            for (int j = 0; j < 4; ++j) areg[j] = ((const float4*)src)[j];
        }
        __syncthreads();   // previous tile fully consumed
        if (AF32) {
            const int arow = tid >> 1, kh = (tid & 1) << 4;
            u16 tmp[16];
            #pragma unroll
            for (int j = 0; j < 4; ++j) {
                tmp[4 * j + 0] = f2bf(areg[j].x);
                tmp[4 * j + 1] = f2bf(areg[j].y);
                tmp[4 * j + 2] = f2bf(areg[j].z);
                tmp[4 * j + 3] = f2bf(areg[j].w);
            }
            #pragma unroll
            for (int h = 0; h < 2; ++h)
                *(u16x8*)&As[arow * 32 + kh + h * 8] = *(u16x8*)&tmp[h * 8];
        } else {
            #pragma unroll
            for (int i = 0; i < 2; ++i) {
                int c = i * 256 + tid;  // 512 chunks of 16B; row = c>>2, koff = (c&3)*8
                const u16* gp = (const u16*)Abase + (size_t)(rowBase + (c >> 2)) * p.lda + kb + (c & 3) * 8;
                char* lp = (char*)As + (i * 256 + wave * 64) * 16;  // wave-uniform base
                __builtin_amdgcn_global_load_lds((const __attribute__((address_space(1))) void*)gp,
                                                 (__attribute__((address_space(3))) void*)lp, 16, 0, 0);
            }
        }
        #pragma unroll
        for (int i = 0; i < 2; ++i) {
            int c = i * 256 + tid;
            const u16* gp = Bbase + (size_t)(colBase + (c >> 2)) * p.ldb + kb + (c & 3) * 8;
            char* lp = (char*)Bs + (i * 256 + wave * 64) * 16;
            __builtin_amdgcn_global_load_lds((const __attribute__((address_space(1))) void*)gp,
                                             (__attribute__((address_space(3))) void*)lp, 16, 0, 0);
        }
        __syncthreads();   // staging complete (vmcnt/lgkmcnt drained by barrier)

        bf16x8 af[4], bfr[4];
        #pragma unroll
        for (int m = 0; m < 4; ++m)
            af[m] = *(const bf16x8*)&As[(wr * 64 + m * 16 + lr) * 32 + g * 8];
        #pragma unroll
        for (int n = 0; n < 4; ++n)
            bfr[n] = *(const bf16x8*)&Bs[(wc * 64 + n * 16 + lr) * 32 + g * 8];
        #pragma unroll
        for (int m = 0; m < 4; ++m)
            #pragma unroll
            for (int n = 0; n < 4; ++n)
                acc[m][n] = __builtin_amdgcn_mfma_f32_16x16x32_bf16(af[m], bfr[n], acc[m][n], 0, 0, 0);
    }

    // epilogue: element (m,n,i): row = rB + m*16 + g*4 + i, col = cB + n*16 + lr
    const int rB = rowBase + wr * 64;
    const int cB = colBase + wc * 64;

    if constexpr (EPI == EPI_PROJ) {
        #pragma unroll
        for (int n = 0; n < 4; ++n) {
            int col = cB + n * 16 + lr;
            float bias = p.bias[col];
            #pragma unroll
            for (int m = 0; m < 4; ++m) {
                int r0 = rB + m * 16 + g * 4;
                #pragma unroll
                for (int i = 0; i < 4; ++i)
                    p.outB[(size_t)(r0 + i) * 512 + col] = f2bf(acc[m][n][i] + bias);
            }
        }
    } else if constexpr (EPI == EPI_PROJV) {
        #pragma unroll
        for (int n = 0; n < 4; ++n) {
            int col = cB + n * 16 + lr;
            float bias = p.bias[col];
            #pragma unroll
            for (int m = 0; m < 4; ++m) {
                int r0 = rB + m * 16 + g * 4;
                int b = r0 >> 11, k0 = r0 & 2047;   // 4 consecutive k, same batch
                u16x4 pk;
                #pragma unroll
                for (int i = 0; i < 4; ++i) pk[i] = f2bf(acc[m][n][i] + bias);
                *(u16x4*)&p.vt[((size_t)b * 512 + col) * 2048 + k0] = pk;
            }
        }
    } else if constexpr (EPI == EPI_LOGITS) {
        const float* qmB = p.qm + z * 2048;
        const float* mdB = p.md + z * 2048;
        const float tau = *p.tauPtr;
        float* outRow = p.outF + (size_t)z * p.outFStride;
        float mdv[4];
        #pragma unroll
        for (int n = 0; n < 4; ++n) mdv[n] = mdB[cB + n * 16 + lr];
        #pragma unroll
        for (int m = 0; m < 4; ++m) {
            int r0 = rB + m * 16 + g * 4;
            #pragma unroll
            for (int i = 0; i < 4; ++i) {
                int q = r0 + i;
                float qv = qmB[q];
                float rs = 0.f;
                #pragma unroll
                for (int n = 0; n < 4; ++n) {
                    float t = tau * (qv + mdv[n]);
                    float u = 1.0f / (1.0f + __expf(-t));
                    u = fminf(fmaxf(u, 1e-6f), 1e6f);
                    float e = __expf(acc[m][n][i] * p.scale * u);
                    outRow[(size_t)q * 2048 + cB + n * 16 + lr] = e;
                    rs += e;
                }
                #pragma unroll
                for (int off = 1; off < 16; off <<= 1) rs += __shfl_xor(rs, off, 64);
                if (lr == 0) redBuf[wc][wr * 64 + m * 16 + g * 4 + i] = rs;
            }
        }
        __syncthreads();
        if (tid < 128) {
            float s = redBuf[0][tid] + redBuf[1][tid];
            int q = rowBase + tid;
            p.partials[((size_t)z * 2048 + q) * 16 + blockIdx.y] = s;
        }
    } else if constexpr (EPI == EPI_PV) {
        #pragma unroll
        for (int n = 0; n < 4; ++n) {
            int col = cB + n * 16 + lr;
            #pragma unroll
            for (int m = 0; m < 4; ++m) {
                int r0 = rB + m * 16 + g * 4;
                size_t gr = (size_t)z * 2048 + r0;
                #pragma unroll
                for (int i = 0; i < 4; ++i)
                    p.outB[(gr + i) * 512 + col] = f2bf(acc[m][n][i]);
            }
        }
    } else {  // EPI_OUT
        #pragma unroll
        for (int n = 0; n < 4; ++n) {
            int col = cB + n * 16 + lr;
            float bias = p.bias[col];
            #pragma unroll
            for (int m = 0; m < 4; ++m) {
                int r0 = rB + m * 16 + g * 4;
                #pragma unroll
                for (int i = 0; i < 4; ++i)
                    p.outF[(size_t)(r0 + i) * 512 + col] = acc[m][n][i] + bias;
            }
        }
    }
}

// convert the 4 weight matrices fp32 -> bf16
__global__ void cvt_weights(const float* a, const float* b, const float* c, const float* d,
                            u16* oa, u16* ob, u16* oc, u16* od) {
    const float* src; u16* dst;
    switch (blockIdx.y) {
        case 0: src = a; dst = oa; break;
        case 1: src = b; dst = ob; break;
        case 2: src = c; dst = oc; break;
        default: src = d; dst = od; break;
    }
    int i = (blockIdx.x * 256 + threadIdx.x) * 4;
    float4 v = *(const float4*)(src + i);
    u16x4 u = { f2bf(v.x), f2bf(v.y), f2bf(v.z), f2bf(v.w) };
    *(u16x4*)(dst + i) = u;
}

__global__ void rowsum_inv(const float* __restrict__ partials, float* __restrict__ invs) {
    int r = blockIdx.x * 256 + threadIdx.x;  // 8192 rows
    float s = 0.f;
    #pragma unroll
    for (int t = 0; t < 16; ++t) s += partials[r * 16 + t];
    invs[r] = 1.0f / s;
}

__global__ void normalize_attn(float* __restrict__ attn, const float* __restrict__ invs) {
    size_t i4 = (size_t)blockIdx.x * 256 + threadIdx.x;  // 4 floats per thread
    int row = (int)(i4 >> 9);  // 512 float4 per 2048-wide row
    float s = invs[row];
    float4 v = ((const float4*)attn)[i4];
    v.x *= s; v.y *= s; v.z *= s; v.w *= s;
    ((float4*)attn)[i4] = v;
}

extern "C" void kernel_launch(void* const* d_in, const int* in_sizes, int n_in,
                              void* d_out, int out_size, void* d_ws, size_t ws_size,
                              hipStream_t stream) {
    const float* qf  = (const float*)d_in[0];
    const float* kf  = (const float*)d_in[1];
    const float* qm  = (const float*)d_in[2];
    const float* md  = (const float*)d_in[3];
    const float* Wq  = (const float*)d_in[4];
    const float* bq  = (const float*)d_in[5];
    const float* Wk  = (const float*)d_in[6];
    const float* bk  = (const float*)d_in[7];
    const float* Wv  = (const float*)d_in[8];
    const float* bv  = (const float*)d_in[9];
    const float* Wo  = (const float*)d_in[10];
    const float* bo  = (const float*)d_in[11];
    const float* tau = (const float*)d_in[12];

    float* out  = (float*)d_out;                       // [4,2048,512]
    float* attn = out + (size_t)4 * 2048 * 512;        // [4,2048,2048]

    u16* Qb   = (u16*)d_ws;                            // [8192,512] bf16
    u16* Kb   = Qb  + (size_t)8192 * 512;
    u16* Vtb  = Kb  + (size_t)8192 * 512;              // [4][512][2048]
    u16* attB = Vtb + (size_t)8192 * 512;              // [8192,512] bf16
    u16* Wqb  = attB + (size_t)8192 * 512;
    u16* Wkb  = Wqb + 512 * 512;
    u16* Wvb  = Wkb + 512 * 512;
    u16* Wob  = Wvb + 512 * 512;
    float* partials = (float*)(Wob + 512 * 512);       // [8192,16]
    float* invs = partials + (size_t)8192 * 16;        // [8192]

    dim3 blk(256);
    cvt_weights<<<dim3(256, 4), blk, 0, stream>>>(Wq, Wk, Wv, Wo, Wqb, Wkb, Wvb, Wob);

    GemmArgs a = {};
    a.lda = 512; a.ldb = 512; a.K = 512;
    // Q projection
    a.A = qf; a.Bm = Wqb; a.bias = bq; a.outB = Qb;
    gemm_bt<EPI_PROJ, true><<<dim3(64, 4, 1), blk, 0, stream>>>(a);
    // K projection
    a.A = kf; a.Bm = Wkb; a.bias = bk; a.outB = Kb;
    gemm_bt<EPI_PROJ, true><<<dim3(64, 4, 1), blk, 0, stream>>>(a);
    // V projection, transposed store
    a.Bm = Wvb; a.bias = bv; a.outB = nullptr; a.vt = Vtb;
    gemm_bt<EPI_PROJV, true><<<dim3(64, 4, 1), blk, 0, stream>>>(a);

    // logits: e = exp((Q K^T)/sqrt(H) * u), per-tile row partial sums
    GemmArgs lg = {};
    lg.A = Qb; lg.aStrideBytes = (long long)2048 * 512 * 2; lg.lda = 512;
    lg.Bm = Kb; lg.bStrideElts = (long long)2048 * 512; lg.ldb = 512;
    lg.K = 512;
    lg.qm = qm; lg.md = md; lg.tauPtr = tau;
    lg.scale = 0.04419417382415922f;  // 1/sqrt(512)
    lg.outF = attn; lg.outFStride = (long long)2048 * 2048;
    lg.partials = partials;
    gemm_bt<EPI_LOGITS, false><<<dim3(16, 16, 4), blk, 0, stream>>>(lg);

    rowsum_inv<<<dim3(32), blk, 0, stream>>>(partials, invs);
    normalize_attn<<<dim3(16384), blk, 0, stream>>>(attn, invs);

    // att = attn @ V  (A fp32 from d_out, B = Vt bf16)
    GemmArgs pv = {};
    pv.A = attn; pv.aStrideBytes = (long long)2048 * 2048 * 4; pv.lda = 2048;
    pv.Bm = Vtb; pv.bStrideElts = (long long)512 * 2048; pv.ldb = 2048;
    pv.K = 2048; pv.outB = attB;
    gemm_bt<EPI_PV, true><<<dim3(16, 4, 4), blk, 0, stream>>>(pv);

    // out = att @ Wo^T + bo
    GemmArgs og = {};
    og.A = attB; og.lda = 512;
    og.Bm = Wob; og.ldb = 512;
    og.K = 512; og.bias = bo; og.outF = out;
    gemm_bt<EPI_OUT, false><<<dim3(64, 4, 1), blk, 0, stream>>>(og);
}

// Round 2
// 143.250 us; speedup vs baseline: 1.4148x; 1.4148x over previous
//
#include <hip/hip_runtime.h>
#include <stdint.h>

#define DEVI static __device__ __forceinline__

typedef unsigned short u16;
typedef short bf16x8 __attribute__((ext_vector_type(8)));
typedef u16 u16x8 __attribute__((ext_vector_type(8)));
typedef u16 u16x4 __attribute__((ext_vector_type(4)));
typedef float f32x4 __attribute__((ext_vector_type(4)));

// round-to-nearest-even float -> bf16
DEVI u16 f2bf(float f) {
    uint32_t u = __builtin_bit_cast(uint32_t, f);
    u += 0x7FFFu + ((u >> 16) & 1u);
    return (u16)(u >> 16);
}
DEVI float bf2f(u16 u) { return __builtin_bit_cast(float, (uint32_t)u << 16); }

struct GemmArgs {
    const void* A;            // fp32 or bf16(u16), row-major [M x K]
    const void* A2;           // second A source (fused projections)
    long long aStrideBytes;   // per-batch stride in BYTES
    int lda;                  // elements
    const u16* Bm;            // [N x K] bf16 (B^T layout)
    long long bStrideElts;
    int ldb;
    int K;                    // per-block K length
    const float* bias; const float* bias2; const float* bias3;
    u16* outB;                // bf16 output
    float* outF;              // fp32 output
    long long outFStride;     // per-batch elements
    const float* qm; const float* md; const float* tauPtr; float scale;
    float* partials;          // [B*2048 * 16] row partial sums
    u16* vt;                  // V transposed dest [B][512][2048]
};

enum { EPI_PROJ = 0, EPI_PROJV = 1, EPI_LOGITS = 2, EPI_PV = 3, EPI_OUT = 4,
       EPI_LOGITSB = 5, EPI_PROJ3 = 6 };

// C[M,N] = A[M,K] @ B[N,K]^T, 128x128 tile, BK=32, 4 waves, 16x16x32 bf16 MFMA.
template <int EPI, bool AF32>
__global__ __launch_bounds__(256, 2) void gemm_bt(GemmArgs p) {
    __shared__ u16 As[128 * 32];
    __shared__ u16 Bs[128 * 32];
    __shared__ float redBuf[2][128];

    const int tid = threadIdx.x;
    const int lane = tid & 63;
    const int wave = tid >> 6;
    const int g = lane >> 4, lr = lane & 15;
    const int wr = wave >> 1, wc = wave & 1;
    const int z = blockIdx.z;
    const int rowBase = blockIdx.x * 128;
    const int colBase = blockIdx.y * 128;

    int batch = z, koff = 0;
    if constexpr (EPI == EPI_PV) { batch = z & 3; koff = (z >> 2) * p.K; }

    const char* Abase;
    const u16* Bbase;
    const float* bias = p.bias;
    if constexpr (EPI == EPI_PROJ3) {
        Abase = (const char*)(z == 0 ? p.A : p.A2);
        Bbase = p.Bm + (size_t)z * 512 * 512;
        bias = (z == 0) ? p.bias : (z == 1 ? p.bias2 : p.bias3);
    } else {
        Abase = (const char*)p.A + (size_t)batch * p.aStrideBytes + (size_t)koff * (AF32 ? 4 : 2);
        Bbase = p.Bm + (size_t)batch * p.bStrideElts + koff;
    }

    f32x4 acc[4][4] = {};

    const int nk = p.K >> 5;
    for (int kt = 0; kt < nk; ++kt) {
        const int kb = kt << 5;
        float4 areg[4];
        if (AF32) {
            const float* Af = (const float*)Abase;
            const int arow = tid >> 1, kh = (tid & 1) << 4;
            const float* src = Af + (size_t)(rowBase + arow) * p.lda + kb + kh;
            #pragma unroll
            for (int j = 0; j < 4; ++j) areg[j] = ((const float4*)src)[j];
        }
        __syncthreads();   // previous tile fully consumed
        if (AF32) {
            const int arow = tid >> 1, kh = (tid & 1) << 4;
            u16 tmp[16];
            #pragma unroll
            for (int j = 0; j < 4; ++j) {
                tmp[4 * j + 0] = f2bf(areg[j].x);
                tmp[4 * j + 1] = f2bf(areg[j].y);
                tmp[4 * j + 2] = f2bf(areg[j].z);
                tmp[4 * j + 3] = f2bf(areg[j].w);
            }
            #pragma unroll
            for (int h = 0; h < 2; ++h)
                *(u16x8*)&As[arow * 32 + kh + h * 8] = *(u16x8*)&tmp[h * 8];
        } else {
            #pragma unroll
            for (int i = 0; i < 2; ++i) {
                int c = i * 256 + tid;  // 512 chunks of 16B; row = c>>2, koff16 = c&3
                const u16* gp = (const u16*)Abase + (size_t)(rowBase + (c >> 2)) * p.lda + kb + (c & 3) * 8;
                char* lp = (char*)As + (i * 256 + wave * 64) * 16;  // wave-uniform base
                __builtin_amdgcn_global_load_lds((const __attribute__((address_space(1))) void*)gp,
                                                 (__attribute__((address_space(3))) void*)lp, 16, 0, 0);
            }
        }
        #pragma unroll
        for (int i = 0; i < 2; ++i) {
            int c = i * 256 + tid;
            const u16* gp = Bbase + (size_t)(colBase + (c >> 2)) * p.ldb + kb + (c & 3) * 8;
            char* lp = (char*)Bs + (i * 256 + wave * 64) * 16;
            __builtin_amdgcn_global_load_lds((const __attribute__((address_space(1))) void*)gp,
                                             (__attribute__((address_space(3))) void*)lp, 16, 0, 0);
        }
        __syncthreads();

        bf16x8 af[4], bfr[4];
        #pragma unroll
        for (int m = 0; m < 4; ++m)
            af[m] = *(const bf16x8*)&As[(wr * 64 + m * 16 + lr) * 32 + g * 8];
        #pragma unroll
        for (int n = 0; n < 4; ++n)
            bfr[n] = *(const bf16x8*)&Bs[(wc * 64 + n * 16 + lr) * 32 + g * 8];
        #pragma unroll
        for (int m = 0; m < 4; ++m)
            #pragma unroll
            for (int n = 0; n < 4; ++n)
                acc[m][n] = __builtin_amdgcn_mfma_f32_16x16x32_bf16(af[m], bfr[n], acc[m][n], 0, 0, 0);
    }

    // epilogue: element (m,n,i): row = rB + m*16 + g*4 + i, col = cB + n*16 + lr
    const int rB = rowBase + wr * 64;
    const int cB = colBase + wc * 64;

    if constexpr (EPI == EPI_PROJ || EPI == EPI_PROJ3) {
        if (EPI == EPI_PROJ || z < 2) {
            u16* dst = (EPI == EPI_PROJ3) ? p.outB + (size_t)z * 8192 * 512 : p.outB;
            #pragma unroll
            for (int n = 0; n < 4; ++n) {
                int col = cB + n * 16 + lr;
                float bv = bias[col];
                #pragma unroll
                for (int m = 0; m < 4; ++m) {
                    int r0 = rB + m * 16 + g * 4;
                    #pragma unroll
                    for (int i = 0; i < 4; ++i)
                        dst[(size_t)(r0 + i) * 512 + col] = f2bf(acc[m][n][i] + bv);
                }
            }
        } else {  // V projection, transposed store
            #pragma unroll
            for (int n = 0; n < 4; ++n) {
                int col = cB + n * 16 + lr;
                float bv = bias[col];
                #pragma unroll
                for (int m = 0; m < 4; ++m) {
                    int r0 = rB + m * 16 + g * 4;
                    int b = r0 >> 11, k0 = r0 & 2047;
                    u16x4 pk;
                    #pragma unroll
                    for (int i = 0; i < 4; ++i) pk[i] = f2bf(acc[m][n][i] + bv);
                    *(u16x4*)&p.vt[((size_t)b * 512 + col) * 2048 + k0] = pk;
                }
            }
        }
    } else if constexpr (EPI == EPI_LOGITS || EPI == EPI_LOGITSB) {
        const float* qmB = p.qm + z * 2048;
        const float* mdB = p.md + z * 2048;
        const float tau = *p.tauPtr;
        float* outRow = p.outF + (size_t)z * p.outFStride;
        float mdv[4];
        #pragma unroll
        for (int n = 0; n < 4; ++n) mdv[n] = mdB[cB + n * 16 + lr];
        #pragma unroll
        for (int m = 0; m < 4; ++m) {
            int r0 = rB + m * 16 + g * 4;
            #pragma unroll
            for (int i = 0; i < 4; ++i) {
                int q = r0 + i;
                float qv = qmB[q];
                float rs = 0.f;
                #pragma unroll
                for (int n = 0; n < 4; ++n) {
                    float t = tau * (qv + mdv[n]);
                    float u = 1.0f / (1.0f + __expf(-t));
                    u = fminf(fmaxf(u, 1e-6f), 1e6f);
                    float e = __expf(acc[m][n][i] * p.scale * u);
                    if (EPI == EPI_LOGITSB)
                        p.outB[((size_t)(z * 2048 + q)) * 2048 + cB + n * 16 + lr] = f2bf(e);
                    else
                        outRow[(size_t)q * 2048 + cB + n * 16 + lr] = e;
                    rs += e;
                }
                #pragma unroll
                for (int off = 1; off < 16; off <<= 1) rs += __shfl_xor(rs, off, 64);
                if (lr == 0) redBuf[wc][wr * 64 + m * 16 + g * 4 + i] = rs;
            }
        }
        __syncthreads();
        if (tid < 128) {
            float s = redBuf[0][tid] + redBuf[1][tid];
            int q = rowBase + tid;
            p.partials[((size_t)z * 2048 + q) * 16 + blockIdx.y] = s;
        }
    } else if constexpr (EPI == EPI_PV) {
        const int split = z >> 2;
        u16* dst = p.outB + (size_t)split * 8192 * 512;
        #pragma unroll
        for (int n = 0; n < 4; ++n) {
            int col = cB + n * 16 + lr;
            #pragma unroll
            for (int m = 0; m < 4; ++m) {
                int r0 = rB + m * 16 + g * 4;
                size_t gr = (size_t)batch * 2048 + r0;
                #pragma unroll
                for (int i = 0; i < 4; ++i)
                    dst[(gr + i) * 512 + col] = f2bf(acc[m][n][i]);
            }
        }
    } else {  // EPI_OUT
        #pragma unroll
        for (int n = 0; n < 4; ++n) {
            int col = cB + n * 16 + lr;
            float bv = p.bias[col];
            #pragma unroll
            for (int m = 0; m < 4; ++m) {
                int r0 = rB + m * 16 + g * 4;
                #pragma unroll
                for (int i = 0; i < 4; ++i)
                    p.outF[(size_t)(r0 + i) * 512 + col] = acc[m][n][i] + bv;
            }
        }
    }
}

// convert the 4 weight matrices fp32 -> bf16 (dsts contiguous)
__global__ void cvt_weights(const float* a, const float* b, const float* c, const float* d,
                            u16* dst) {
    const float* src;
    switch (blockIdx.y) {
        case 0: src = a; break;
        case 1: src = b; break;
        case 2: src = c; break;
        default: src = d; break;
    }
    int i = (blockIdx.x * 256 + threadIdx.x) * 4;
    float4 v = *(const float4*)(src + i);
    u16x4 u = { f2bf(v.x), f2bf(v.y), f2bf(v.z), f2bf(v.w) };
    *(u16x4*)(dst + (size_t)blockIdx.y * 512 * 512 + i) = u;
}

__global__ void rowsum_inv(const float* __restrict__ partials, float* __restrict__ invs) {
    int r = blockIdx.x * 256 + threadIdx.x;  // 8192 rows
    float s = 0.f;
    #pragma unroll
    for (int t = 0; t < 16; ++t) s += partials[r * 16 + t];
    invs[r] = 1.0f / s;
}

// fp32-e in-place normalize (fallback path)
__global__ void normalize_attn(float* __restrict__ attn, const float* __restrict__ invs) {
    size_t i4 = (size_t)blockIdx.x * 256 + threadIdx.x;  // 4 floats per thread
    int row = (int)(i4 >> 9);
    float s = invs[row];
    float4 v = ((const float4*)attn)[i4];
    v.x *= s; v.y *= s; v.z *= s; v.w *= s;
    ((float4*)attn)[i4] = v;
}

// bf16-e -> fp32 normalized attn
__global__ void normalize_bf(const u16* __restrict__ e, float* __restrict__ attn,
                             const float* __restrict__ invs) {
    size_t i8 = (size_t)blockIdx.x * 256 + threadIdx.x;  // 8 elems per thread
    size_t e0 = i8 * 8;
    int row = (int)(e0 >> 11);
    float s = invs[row];
    u16x8 v = *(const u16x8*)(e + e0);
    float4 a, b;
    a.x = bf2f(v[0]) * s; a.y = bf2f(v[1]) * s; a.z = bf2f(v[2]) * s; a.w = bf2f(v[3]) * s;
    b.x = bf2f(v[4]) * s; b.y = bf2f(v[5]) * s; b.z = bf2f(v[6]) * s; b.w = bf2f(v[7]) * s;
    ((float4*)(attn + e0))[0] = a;
    ((float4*)(attn + e0))[1] = b;
}

// partial0 + partial1, optional inv scaling, -> bf16 att
__global__ void pv_reduce(const u16* __restrict__ part, const float* __restrict__ invs,
                          u16* __restrict__ attB) {
    size_t i8 = (size_t)blockIdx.x * 256 + threadIdx.x;  // 8 elems per thread
    size_t e0 = i8 * 8;
    int row = (int)(e0 >> 9);  // /512
    float s = invs ? invs[row] : 1.0f;
    u16x8 p0 = *(const u16x8*)(part + e0);
    u16x8 p1 = *(const u16x8*)(part + (size_t)8192 * 512 + e0);
    u16x8 o;
    #pragma unroll
    for (int j = 0; j < 8; ++j) o[j] = f2bf((bf2f(p0[j]) + bf2f(p1[j])) * s);
    *(u16x8*)(attB + e0) = o;
}

extern "C" void kernel_launch(void* const* d_in, const int* in_sizes, int n_in,
                              void* d_out, int out_size, void* d_ws, size_t ws_size,
                              hipStream_t stream) {
    const float* qf  = (const float*)d_in[0];
    const float* kf  = (const float*)d_in[1];
    const float* qm  = (const float*)d_in[2];
    const float* md  = (const float*)d_in[3];
    const float* Wq  = (const float*)d_in[4];
    const float* bq  = (const float*)d_in[5];
    const float* Wk  = (const float*)d_in[6];
    const float* bk  = (const float*)d_in[7];
    const float* Wv  = (const float*)d_in[8];
    const float* bv  = (const float*)d_in[9];
    const float* Wo  = (const float*)d_in[10];
    const float* bo  = (const float*)d_in[11];
    const float* tau = (const float*)d_in[12];

    float* out  = (float*)d_out;                       // [4,2048,512]
    float* attn = out + (size_t)4 * 2048 * 512;        // [4,2048,2048]

    const size_t NV = (size_t)8192 * 512;              // 4.19M elems
    u16* Qb   = (u16*)d_ws;                            // [8192,512] bf16
    u16* Kb   = Qb + NV;
    u16* Vtb  = Kb + NV;                               // [4][512][2048]
    u16* Wqb  = Vtb + NV;                              // Wq,Wk,Wv,Wo contiguous
    u16* Wob  = Wqb + (size_t)3 * 512 * 512;
    float* partials = (float*)(Wqb + (size_t)4 * 512 * 512);  // [8192,16]
    float* invs = partials + (size_t)8192 * 16;
    u16* attE = (u16*)(invs + 8192);                   // [4,2048,2048] bf16 (big path)
    size_t need = (size_t)((char*)(attE + (size_t)4 * 2048 * 2048) - (char*)d_ws);
    const bool big = ws_size >= need;

    u16* partialPV = Qb;   // aliases Qb+Kb (dead after logits): [2][8192][512] bf16
    u16* attB = Vtb;       // aliases Vtb (dead after PV)

    dim3 blk(256);
    cvt_weights<<<dim3(256, 4), blk, 0, stream>>>(Wq, Wk, Wv, Wo, Wqb);

    // fused Q/K/V projections
    GemmArgs a = {};
    a.A = qf; a.A2 = kf; a.lda = 512; a.ldb = 512; a.K = 512;
    a.Bm = Wqb; a.bias = bq; a.bias2 = bk; a.bias3 = bv;
    a.outB = Qb; a.vt = Vtb;
    gemm_bt<EPI_PROJ3, true><<<dim3(64, 4, 3), blk, 0, stream>>>(a);

    // logits: e = exp((Q K^T)/sqrt(H) * u), per-tile row partial sums
    GemmArgs lg = {};
    lg.A = Qb; lg.aStrideBytes = (long long)2048 * 512 * 2; lg.lda = 512;
    lg.Bm = Kb; lg.bStrideElts = (long long)2048 * 512; lg.ldb = 512;
    lg.K = 512;
    lg.qm = qm; lg.md = md; lg.tauPtr = tau;
    lg.scale = 0.04419417382415922f;  // 1/sqrt(512)
    lg.partials = partials;
    if (big) {
        lg.outB = attE;
        gemm_bt<EPI_LOGITSB, false><<<dim3(16, 16, 4), blk, 0, stream>>>(lg);
    } else {
        lg.outF = attn; lg.outFStride = (long long)2048 * 2048;
        gemm_bt<EPI_LOGITS, false><<<dim3(16, 16, 4), blk, 0, stream>>>(lg);
    }

    rowsum_inv<<<dim3(32), blk, 0, stream>>>(partials, invs);

    if (big)
        normalize_bf<<<dim3(8192), blk, 0, stream>>>(attE, attn, invs);
    else
        normalize_attn<<<dim3(16384), blk, 0, stream>>>(attn, invs);

    // att_partial[split] = e[., split*1024 : +1024] @ V  (split-K=2)
    GemmArgs pv = {};
    pv.Bm = Vtb; pv.bStrideElts = (long long)512 * 2048; pv.ldb = 2048;
    pv.K = 1024; pv.outB = partialPV; pv.lda = 2048;
    if (big) {
        pv.A = attE; pv.aStrideBytes = (long long)2048 * 2048 * 2;
        gemm_bt<EPI_PV, false><<<dim3(16, 4, 8), blk, 0, stream>>>(pv);
        pv_reduce<<<dim3(2048), blk, 0, stream>>>(partialPV, invs, attB);
    } else {
        pv.A = attn; pv.aStrideBytes = (long long)2048 * 2048 * 4;
        gemm_bt<EPI_PV, true><<<dim3(16, 4, 8), blk, 0, stream>>>(pv);
        pv_reduce<<<dim3(2048), blk, 0, stream>>>(partialPV, nullptr, attB);
    }

    // out = att @ Wo^T + bo
    GemmArgs og = {};
    og.A = attB; og.lda = 512;
    og.Bm = Wob; og.ldb = 512;
    og.K = 512; og.bias = bo; og.outF = out;
    gemm_bt<EPI_OUT, false><<<dim3(64, 4, 1), blk, 0, stream>>>(og);
}

// Round 3
// 132.064 us; speedup vs baseline: 1.5346x; 1.0847x over previous
//
#include <hip/hip_runtime.h>
#include <stdint.h>

#define DEVI static __device__ __forceinline__

typedef unsigned short u16;
typedef short bf16x8 __attribute__((ext_vector_type(8)));
typedef u16 u16x8 __attribute__((ext_vector_type(8)));
typedef u16 u16x4 __attribute__((ext_vector_type(4)));
typedef float f32x4 __attribute__((ext_vector_type(4)));

// round-to-nearest-even float -> bf16
DEVI u16 f2bf(float f) {
    uint32_t u = __builtin_bit_cast(uint32_t, f);
    u += 0x7FFFu + ((u >> 16) & 1u);
    return (u16)(u >> 16);
}
DEVI float bf2f(u16 u) { return __builtin_bit_cast(float, (uint32_t)u << 16); }

struct GemmArgs {
    const void* A;            // A source: bf16 / fp32 / bf16-partial-pair per AMODE
    const void* A2;           // second A source (fused projections)
    long long aStrideBytes;   // per-batch stride in BYTES
    int lda;                  // elements
    const u16* Bm;            // [N x K] bf16 (B^T layout)
    long long bStrideElts;
    int ldb;
    int K;                    // per-block K length
    const float* bias; const float* bias2; const float* bias3;
    u16* outB;                // bf16 output
    float* outF;              // fp32 output
    long long outFStride;     // per-batch elements
    const float* qm; const float* md; const float* tauPtr; float scale;
    float* partials;          // [B*2048 * 16] row partial sums
    const float* invsPtr;     // [8192] 1/rowsum
    u16* vt;                  // V transposed dest [B][512][2048]
};

enum { EPI_PROJ3 = 0, EPI_LOGITS = 1, EPI_LOGITSB = 2, EPI_PV = 3, EPI_OUT = 4 };
// AMODE: 0 = bf16 A via global_load_lds; 1 = fp32 A reg-stage+convert; 2 = sum of two
// bf16 split-K partials (+invs scale) reg-staged.

// C[M,N] = A[M,K] @ B[N,K]^T, TMx128 tile, BK=32, 4 waves, 16x16x32 bf16 MFMA.
template <int EPI, int AMODE, int TM>
__global__ __launch_bounds__(256, 2) void gemm_bt(GemmArgs p) {
    constexpr int NF = (TM == 128) ? 4 : 2;
    __shared__ u16 As[TM * 32];
    __shared__ u16 Bs[128 * 32];
    __shared__ float redBuf[2][128];

    const int tid = threadIdx.x;
    const int lane = tid & 63;
    const int wave = tid >> 6;
    const int g = lane >> 4, lr = lane & 15;
    const int waveRowBase = (TM == 128) ? (wave >> 1) * 64 : 0;
    const int waveColBase = (TM == 128) ? (wave & 1) * 64 : wave * 32;
    const int z = blockIdx.z;
    const int rowBase = blockIdx.x * TM;
    const int colBase = blockIdx.y * 128;

    int batch = z, koff = 0;
    if constexpr (EPI == EPI_PV) { batch = z & 3; koff = (z >> 2) * p.K; }

    const char* Abase;
    const u16* Bbase;
    const float* bias = p.bias;
    if constexpr (EPI == EPI_PROJ3) {
        Abase = (const char*)(z == 0 ? p.A : p.A2);
        Bbase = p.Bm + (size_t)z * 512 * 512;
        bias = (z == 0) ? p.bias : (z == 1 ? p.bias2 : p.bias3);
    } else {
        Abase = (const char*)p.A + (size_t)batch * p.aStrideBytes + (size_t)koff * (AMODE == 1 ? 4 : 2);
        Bbase = p.Bm + (size_t)batch * p.bStrideElts + koff;
    }

    // ---- fused attn-normalize blocks (PV big path, blockIdx.y==4) ----
    if constexpr (EPI == EPI_PV && AMODE == 0) {
        if (blockIdx.y == 4) {
            // rows [rowBase, +128), key-cols [koff, +1024): attn = e * invs, fp32
            const u16* e = (const u16*)Abase + (size_t)rowBase * 2048;
            float* attnOut = p.outF + (size_t)batch * p.outFStride + (size_t)rowBase * 2048 + koff;
            const float* invs = p.invsPtr + batch * 2048 + rowBase;
            #pragma unroll 4
            for (int it = 0; it < 64; ++it) {
                int cc = it * 256 + tid;
                int row = cc >> 7, colc = (cc & 127) * 8;
                float s = invs[row];
                u16x8 v = *(const u16x8*)(e + (size_t)row * 2048 + colc);
                float4 f0, f1;
                f0.x = bf2f(v[0]) * s; f0.y = bf2f(v[1]) * s;
                f0.z = bf2f(v[2]) * s; f0.w = bf2f(v[3]) * s;
                f1.x = bf2f(v[4]) * s; f1.y = bf2f(v[5]) * s;
                f1.z = bf2f(v[6]) * s; f1.w = bf2f(v[7]) * s;
                float* dst = attnOut + (size_t)row * 2048 + colc;
                ((float4*)dst)[0] = f0;
                ((float4*)dst)[1] = f1;
            }
            return;
        }
    }

    f32x4 acc[4][NF] = {};

    // AMODE==2 invariants (hoisted)
    const int arow2 = tid >> 2, kh2 = (tid & 3) << 3;
    const u16* pa0 = nullptr; const u16* pa1 = nullptr; float sInv = 1.0f;
    if constexpr (AMODE == 2) {
        pa0 = (const u16*)p.A + (size_t)(rowBase + arow2) * 512 + kh2;
        pa1 = pa0 + (size_t)8192 * 512;
        sInv = p.invsPtr ? p.invsPtr[rowBase + arow2] : 1.0f;
    }

    const int nk = p.K >> 5;
    for (int kt = 0; kt < nk; ++kt) {
        const int kb = kt << 5;
        float4 areg[4];
        u16x8 a0, a1;
        if constexpr (AMODE == 1) {
            const float* Af = (const float*)Abase;
            const int arow = tid >> 1, kh = (tid & 1) << 4;
            const float* src = Af + (size_t)(rowBase + arow) * p.lda + kb + kh;
            #pragma unroll
            for (int j = 0; j < 4; ++j) areg[j] = ((const float4*)src)[j];
        } else if constexpr (AMODE == 2) {
            a0 = *(const u16x8*)(pa0 + kb);
            a1 = *(const u16x8*)(pa1 + kb);
        }
        __syncthreads();   // previous tile fully consumed
        if constexpr (AMODE == 1) {
            const int arow = tid >> 1, kh = (tid & 1) << 4;
            u16 tmp[16];
            #pragma unroll
            for (int j = 0; j < 4; ++j) {
                tmp[4 * j + 0] = f2bf(areg[j].x);
                tmp[4 * j + 1] = f2bf(areg[j].y);
                tmp[4 * j + 2] = f2bf(areg[j].z);
                tmp[4 * j + 3] = f2bf(areg[j].w);
            }
            #pragma unroll
            for (int h = 0; h < 2; ++h)
                *(u16x8*)&As[arow * 32 + kh + h * 8] = *(u16x8*)&tmp[h * 8];
        } else if constexpr (AMODE == 2) {
            u16 tmp[8];
            #pragma unroll
            for (int j = 0; j < 8; ++j)
                tmp[j] = f2bf((bf2f(a0[j]) + bf2f(a1[j])) * sInv);
            *(u16x8*)&As[arow2 * 32 + kh2] = *(u16x8*)tmp;
        } else {
            #pragma unroll
            for (int i = 0; i < TM / 64; ++i) {
                int c = i * 256 + tid;  // 16B chunks; row = c>>2, k-off = (c&3)*8
                const u16* gp = (const u16*)Abase + (size_t)(rowBase + (c >> 2)) * p.lda + kb + (c & 3) * 8;
                char* lp = (char*)As + (i * 256 + wave * 64) * 16;  // wave-uniform base
                __builtin_amdgcn_global_load_lds((const __attribute__((address_space(1))) void*)gp,
                                                 (__attribute__((address_space(3))) void*)lp, 16, 0, 0);
            }
        }
        #pragma unroll
        for (int i = 0; i < 2; ++i) {
            int c = i * 256 + tid;
            const u16* gp = Bbase + (size_t)(colBase + (c >> 2)) * p.ldb + kb + (c & 3) * 8;
            char* lp = (char*)Bs + (i * 256 + wave * 64) * 16;
            __builtin_amdgcn_global_load_lds((const __attribute__((address_space(1))) void*)gp,
                                             (__attribute__((address_space(3))) void*)lp, 16, 0, 0);
        }
        __syncthreads();

        bf16x8 af[4], bfr[NF];
        #pragma unroll
        for (int m = 0; m < 4; ++m)
            af[m] = *(const bf16x8*)&As[(waveRowBase + m * 16 + lr) * 32 + g * 8];
        #pragma unroll
        for (int n = 0; n < NF; ++n)
            bfr[n] = *(const bf16x8*)&Bs[(waveColBase + n * 16 + lr) * 32 + g * 8];
        #pragma unroll
        for (int m = 0; m < 4; ++m)
            #pragma unroll
            for (int n = 0; n < NF; ++n)
                acc[m][n] = __builtin_amdgcn_mfma_f32_16x16x32_bf16(af[m], bfr[n], acc[m][n], 0, 0, 0);
    }

    // epilogue: element (m,n,i): row = rB + m*16 + g*4 + i, col = cB + n*16 + lr
    const int rB = rowBase + waveRowBase;
    const int cB = colBase + waveColBase;

    if constexpr (EPI == EPI_PROJ3) {
        if (z < 2) {
            u16* dst = p.outB + (size_t)z * 8192 * 512;
            #pragma unroll
            for (int n = 0; n < NF; ++n) {
                int col = cB + n * 16 + lr;
                float bv = bias[col];
                #pragma unroll
                for (int m = 0; m < 4; ++m) {
                    int r0 = rB + m * 16 + g * 4;
                    #pragma unroll
                    for (int i = 0; i < 4; ++i)
                        dst[(size_t)(r0 + i) * 512 + col] = f2bf(acc[m][n][i] + bv);
                }
            }
        } else {  // V projection, transposed store
            #pragma unroll
            for (int n = 0; n < NF; ++n) {
                int col = cB + n * 16 + lr;
                float bv = bias[col];
                #pragma unroll
                for (int m = 0; m < 4; ++m) {
                    int r0 = rB + m * 16 + g * 4;
                    int b = r0 >> 11, k0 = r0 & 2047;
                    u16x4 pk;
                    #pragma unroll
                    for (int i = 0; i < 4; ++i) pk[i] = f2bf(acc[m][n][i] + bv);
                    *(u16x4*)&p.vt[((size_t)b * 512 + col) * 2048 + k0] = pk;
                }
            }
        }
    } else if constexpr (EPI == EPI_LOGITS || EPI == EPI_LOGITSB) {
        const float* qmB = p.qm + z * 2048;
        const float* mdB = p.md + z * 2048;
        const float tau = *p.tauPtr;
        float* outRow = p.outF + (size_t)z * p.outFStride;
        float mdv[NF];
        #pragma unroll
        for (int n = 0; n < NF; ++n) mdv[n] = mdB[cB + n * 16 + lr];
        #pragma unroll
        for (int m = 0; m < 4; ++m) {
            int r0 = rB + m * 16 + g * 4;
            #pragma unroll
            for (int i = 0; i < 4; ++i) {
                int q = r0 + i;
                float qv = qmB[q];
                float rs = 0.f;
                #pragma unroll
                for (int n = 0; n < NF; ++n) {
                    float t = tau * (qv + mdv[n]);
                    float u = 1.0f / (1.0f + __expf(-t));
                    u = fminf(fmaxf(u, 1e-6f), 1e6f);
                    float e = __expf(acc[m][n][i] * p.scale * u);
                    if (EPI == EPI_LOGITSB)
                        p.outB[((size_t)(z * 2048 + q)) * 2048 + cB + n * 16 + lr] = f2bf(e);
                    else
                        outRow[(size_t)q * 2048 + cB + n * 16 + lr] = e;
                    rs += e;
                }
                #pragma unroll
                for (int off = 1; off < 16; off <<= 1) rs += __shfl_xor(rs, off, 64);
                if (lr == 0) redBuf[wave & 1][waveRowBase + m * 16 + g * 4 + i] = rs;
            }
        }
        __syncthreads();
        if (tid < 128) {
            float s = redBuf[0][tid] + redBuf[1][tid];
            int q = rowBase + tid;
            p.partials[((size_t)z * 2048 + q) * 16 + blockIdx.y] = s;
        }
    } else if constexpr (EPI == EPI_PV) {
        const int split = z >> 2;
        u16* dst = p.outB + (size_t)split * 8192 * 512;
        #pragma unroll
        for (int n = 0; n < NF; ++n) {
            int col = cB + n * 16 + lr;
            #pragma unroll
            for (int m = 0; m < 4; ++m) {
                int r0 = rB + m * 16 + g * 4;
                size_t gr = (size_t)batch * 2048 + r0;
                #pragma unroll
                for (int i = 0; i < 4; ++i)
                    dst[(gr + i) * 512 + col] = f2bf(acc[m][n][i]);
            }
        }
    } else {  // EPI_OUT
        #pragma unroll
        for (int n = 0; n < NF; ++n) {
            int col = cB + n * 16 + lr;
            float bv = p.bias[col];
            #pragma unroll
            for (int m = 0; m < 4; ++m) {
                int r0 = rB + m * 16 + g * 4;
                #pragma unroll
                for (int i = 0; i < 4; ++i)
                    p.outF[(size_t)(r0 + i) * 512 + col] = acc[m][n][i] + bv;
            }
        }
    }
}

// convert the 4 weight matrices fp32 -> bf16 (dsts contiguous)
__global__ void cvt_weights(const float* a, const float* b, const float* c, const float* d,
                            u16* dst) {
    const float* src;
    switch (blockIdx.y) {
        case 0: src = a; break;
        case 1: src = b; break;
        case 2: src = c; break;
        default: src = d; break;
    }
    int i = (blockIdx.x * 256 + threadIdx.x) * 4;
    float4 v = *(const float4*)(src + i);
    u16x4 u = { f2bf(v.x), f2bf(v.y), f2bf(v.z), f2bf(v.w) };
    *(u16x4*)(dst + (size_t)blockIdx.y * 512 * 512 + i) = u;
}

__global__ void rowsum_inv(const float* __restrict__ partials, float* __restrict__ invs) {
    int r = blockIdx.x * 256 + threadIdx.x;  // 8192 rows
    float s = 0.f;
    #pragma unroll
    for (int t = 0; t < 16; ++t) s += partials[r * 16 + t];
    invs[r] = 1.0f / s;
}

// fp32-e in-place normalize (small-ws fallback path)
__global__ void normalize_attn(float* __restrict__ attn, const float* __restrict__ invs) {
    size_t i4 = (size_t)blockIdx.x * 256 + threadIdx.x;  // 4 floats per thread
    int row = (int)(i4 >> 9);
    float s = invs[row];
    float4 v = ((const float4*)attn)[i4];
    v.x *= s; v.y *= s; v.z *= s; v.w *= s;
    ((float4*)attn)[i4] = v;
}

extern "C" void kernel_launch(void* const* d_in, const int* in_sizes, int n_in,
                              void* d_out, int out_size, void* d_ws, size_t ws_size,
                              hipStream_t stream) {
    const float* qf  = (const float*)d_in[0];
    const float* kf  = (const float*)d_in[1];
    const float* qm  = (const float*)d_in[2];
    const float* md  = (const float*)d_in[3];
    const float* Wq  = (const float*)d_in[4];
    const float* bq  = (const float*)d_in[5];
    const float* Wk  = (const float*)d_in[6];
    const float* bk  = (const float*)d_in[7];
    const float* Wv  = (const float*)d_in[8];
    const float* bv  = (const float*)d_in[9];
    const float* Wo  = (const float*)d_in[10];
    const float* bo  = (const float*)d_in[11];
    const float* tau = (const float*)d_in[12];

    float* out  = (float*)d_out;                       // [4,2048,512]
    float* attn = out + (size_t)4 * 2048 * 512;        // [4,2048,2048]

    const size_t NV = (size_t)8192 * 512;
    u16* Qb   = (u16*)d_ws;                            // [8192,512] bf16
    u16* Kb   = Qb + NV;
    u16* Vtb  = Kb + NV;                               // [4][512][2048]
    u16* Wqb  = Vtb + NV;                              // Wq,Wk,Wv,Wo contiguous
    u16* Wob  = Wqb + (size_t)3 * 512 * 512;
    float* partials = (float*)(Wqb + (size_t)4 * 512 * 512);  // [8192,16]
    float* invs = partials + (size_t)8192 * 16;
    u16* attE = (u16*)(invs + 8192);                   // [4,2048,2048] bf16 (big path)
    size_t need = (size_t)((char*)(attE + (size_t)4 * 2048 * 2048) - (char*)d_ws);
    const bool big = ws_size >= need;

    u16* partialPV = Qb;   // aliases Qb+Kb (dead after logits): [2][8192][512] bf16

    dim3 blk(256);
    cvt_weights<<<dim3(256, 4), blk, 0, stream>>>(Wq, Wk, Wv, Wo, Wqb);

    // fused Q/K/V projections
    GemmArgs a = {};
    a.A = qf; a.A2 = kf; a.lda = 512; a.ldb = 512; a.K = 512;
    a.Bm = Wqb; a.bias = bq; a.bias2 = bk; a.bias3 = bv;
    a.outB = Qb; a.vt = Vtb;
    gemm_bt<EPI_PROJ3, 1, 128><<<dim3(64, 4, 3), blk, 0, stream>>>(a);

    // logits: e = exp((Q K^T)/sqrt(H) * u), per-tile row partial sums
    GemmArgs lg = {};
    lg.A = Qb; lg.aStrideBytes = (long long)2048 * 512 * 2; lg.lda = 512;
    lg.Bm = Kb; lg.bStrideElts = (long long)2048 * 512; lg.ldb = 512;
    lg.K = 512;
    lg.qm = qm; lg.md = md; lg.tauPtr = tau;
    lg.scale = 0.04419417382415922f;  // 1/sqrt(512)
    lg.partials = partials;
    if (big) {
        lg.outB = attE;
        gemm_bt<EPI_LOGITSB, 0, 128><<<dim3(16, 16, 4), blk, 0, stream>>>(lg);
    } else {
        lg.outF = attn; lg.outFStride = (long long)2048 * 2048;
        gemm_bt<EPI_LOGITS, 0, 128><<<dim3(16, 16, 4), blk, 0, stream>>>(lg);
    }

    rowsum_inv<<<dim3(32), blk, 0, stream>>>(partials, invs);

    // att_partial[split] = e[., split*1024 : +1024] @ V  (split-K=2)
    // big path: blockIdx.y==4 blocks concurrently write normalized fp32 attn
    GemmArgs pv = {};
    pv.Bm = Vtb; pv.bStrideElts = (long long)512 * 2048; pv.ldb = 2048;
    pv.K = 1024; pv.outB = partialPV; pv.lda = 2048;
    pv.invsPtr = invs;
    if (big) {
        pv.A = attE; pv.aStrideBytes = (long long)2048 * 2048 * 2;
        pv.outF = attn; pv.outFStride = (long long)2048 * 2048;
        gemm_bt<EPI_PV, 0, 128><<<dim3(16, 5, 8), blk, 0, stream>>>(pv);
    } else {
        normalize_attn<<<dim3(16384), blk, 0, stream>>>(attn, invs);
        pv.A = attn; pv.aStrideBytes = (long long)2048 * 2048 * 4;
        gemm_bt<EPI_PV, 1, 128><<<dim3(16, 4, 8), blk, 0, stream>>>(pv);
    }

    // out = (partial0 + partial1)*invs @ Wo^T + bo  (reduce fused into A-stage)
    GemmArgs og = {};
    og.A = partialPV; og.lda = 512;
    og.Bm = Wob; og.ldb = 512;
    og.K = 512; og.bias = bo; og.outF = out;
    og.invsPtr = big ? invs : nullptr;
    gemm_bt<EPI_OUT, 2, 64><<<dim3(128, 4, 1), blk, 0, stream>>>(og);
}